// Round 8
// baseline (586.978 us; speedup 1.0000x reference)
//
#include <hip/hip_runtime.h>
#include <cfloat>

#define BATCH 4
#define P 8192
#define C 64
#define KNN 16
#define NPTS (BATCH * P)        // 32768
#define NEDGE (NPTS * KNN)      // 524288
#define EPSV 1e-5f
#define SLOPE 0.2f
#define NQ 2                    // column-range split per row-tile
#define QCOLS (P / NQ)          // 4096 cols per block
#define NPART 4                 // partial lists per row = NQ * 2 col-waves

typedef __attribute__((ext_vector_type(8))) short bf16x8;
typedef __attribute__((ext_vector_type(16))) float f32x16;

// ---------------- workspace layout (float element offsets) ----------------
// U      : [NPTS][C]   @ 0          (2097152)   written AFTER knn
// V      : [NPTS][C]   @ 2097152    (2097152)   written AFTER knn
// xfh/xfm/xfl bf16 frags alias U/V region (dead after knn)
// sq     : [NPTS]      @ 4194304    (32768)
// stats  : [128]       @ 4227072
// sshift : [128]       @ 4227200
// idx    : int[NEDGE]  @ 4227328    (524288)
// pv     : [NPTS][4][16] float @ 4751616 (2097152)
// pi     : [NPTS][4][16] int   @ 6848768 (2097152)
// total = 8945920 floats = 34.1 MB

__device__ __forceinline__ unsigned short f2bf(float f) {
    unsigned u = __float_as_uint(f);
    u += 0x7FFFu + ((u >> 16) & 1u);
    return (unsigned short)(u >> 16);
}
__device__ __forceinline__ float bf2f(unsigned short s) {
    return __uint_as_float(((unsigned)s) << 16);
}

// ---------------------------------------------------------------------------
// K0: fragment-layout 3-way bf16 split of x + exact fp32 row norms.
// xf[(g*4+kk)*64 + lane] (uint4 = 8 bf16) holds point g*32+(lane&31),
// k = kk*16 + (lane>>5)*8 .. +8  — the mfma_f32_32x32x16_bf16 operand map.
// ---------------------------------------------------------------------------
__global__ void prep_frag(const float* __restrict__ x, uint4* __restrict__ xfh,
                          uint4* __restrict__ xfm, uint4* __restrict__ xfl,
                          float* __restrict__ sq) {
    __shared__ float part[32][9];
    int tid = threadIdx.x;
    int ptl = tid >> 3, j8 = tid & 7;
    int g = blockIdx.x;
    int p = g * 32 + ptl;
    const float4* xp = (const float4*)(x + (size_t)p * C + j8 * 8);
    float4 a = xp[0], b = xp[1];
    float v[8] = {a.x, a.y, a.z, a.w, b.x, b.y, b.z, b.w};
    unsigned short hs[8], ms[8], ls[8];
    float ssum = 0.f;
#pragma unroll
    for (int e = 0; e < 8; ++e) {
        float xv = v[e];
        ssum = fmaf(xv, xv, ssum);
        unsigned short h = f2bf(xv);
        float r1 = xv - bf2f(h);
        unsigned short m = f2bf(r1);
        float r2 = r1 - bf2f(m);
        unsigned short l = f2bf(r2);
        hs[e] = h; ms[e] = m; ls[e] = l;
    }
    int dst = (g * 4 + (j8 >> 1)) * 64 + ptl + 32 * (j8 & 1);
    uint4 ph, pm, pl;
    ph.x = (unsigned)hs[0] | ((unsigned)hs[1] << 16);
    ph.y = (unsigned)hs[2] | ((unsigned)hs[3] << 16);
    ph.z = (unsigned)hs[4] | ((unsigned)hs[5] << 16);
    ph.w = (unsigned)hs[6] | ((unsigned)hs[7] << 16);
    pm.x = (unsigned)ms[0] | ((unsigned)ms[1] << 16);
    pm.y = (unsigned)ms[2] | ((unsigned)ms[3] << 16);
    pm.z = (unsigned)ms[4] | ((unsigned)ms[5] << 16);
    pm.w = (unsigned)ms[6] | ((unsigned)ms[7] << 16);
    pl.x = (unsigned)ls[0] | ((unsigned)ls[1] << 16);
    pl.y = (unsigned)ls[2] | ((unsigned)ls[3] << 16);
    pl.z = (unsigned)ls[4] | ((unsigned)ls[5] << 16);
    pl.w = (unsigned)ls[6] | ((unsigned)ls[7] << 16);
    xfh[dst] = ph; xfm[dst] = pm; xfl[dst] = pl;
    part[ptl][j8] = ssum;
    __syncthreads();
    if (j8 == 0) {
        float s = 0.f;
#pragma unroll
        for (int k = 0; k < 8; ++k) s += part[ptl][k];
        sq[p] = s;
    }
}

// ---------------------------------------------------------------------------
// K1: KNN partial — WAVE-AUTONOMOUS, zero barriers in the K-loop.
// WG = (batch, 64-row tile, column half). Wave (wr,wc) computes its 32x32
// quadrant and keeps a PRIVATE top-16 per row for its col-half in its own
// LDS region (wave-internal LDS is program-order consistent — no
// __syncthreads needed). 4 partial lists per row merged by merge_kernel.
// Chunk 0 floods slotted (no atomics); later chunks append survivors
// (ids = 5-bit col-sub as ushort). Lanes 0-31 merge one row each.
// K-halved B staging (6 frags live, not 12) + sched_barrier(0) caps
// registers so __launch_bounds__(256,4) fits without the r7 spill
// (unified VGPR+AGPR budget 128/wave; A48 + B24 + acc32 + misc ~20).
// ---------------------------------------------------------------------------
__global__ __launch_bounds__(256, 4) void knn_kernel(const uint4* __restrict__ xfh,
                                                     const uint4* __restrict__ xfm,
                                                     const uint4* __restrict__ xfl,
                                                     const float* __restrict__ sq,
                                                     float* __restrict__ pv,
                                                     int* __restrict__ pi) {
    __shared__ float          bufv[4 * 32 * 33];   // per-wave survivor values
    __shared__ unsigned short bufi[4 * 32 * 33];   // per-wave survivor col-subs
    __shared__ int            idL [4 * 32 * 17];   // per-wave top-16 ids
    __shared__ int            cntL[4 * 32];
    __shared__ float          worstL[4 * 32];

    int tid = threadIdx.x;
    int b = blockIdx.x & 3;              // batch -> XCDs {b, b+4}: frags L2-resident
    int t = blockIdx.x >> 2;
    int tile = t & 127;
    int half = t >> 7;
    int bglob = b * P;
    int r0 = tile * 64;
    int colbase = half * QCOLS;
    int w = tid >> 6, lane = tid & 63;
    int wr = w & 1, wc = w >> 1;

    float*          bufvW = bufv + w * (32 * 33);
    unsigned short* bufiW = bufi + w * (32 * 33);
    int*            idLW  = idL  + w * (32 * 17);
    int*            cntW  = cntL + w * 32;
    float*          worstW = worstL + w * 32;

    if (lane < 32) { cntW[lane] = 0; worstW[lane] = FLT_MAX; }

    // persistent A fragments for this wave's 32 rows (48 VGPRs)
    int gA = ((bglob + r0) >> 5) + wr;
    bf16x8 Ah[4], Am[4], Al[4];
#pragma unroll
    for (int kk = 0; kk < 4; ++kk) {
        Ah[kk] = __builtin_bit_cast(bf16x8, xfh[(gA * 4 + kk) * 64 + lane]);
        Am[kk] = __builtin_bit_cast(bf16x8, xfm[(gA * 4 + kk) * 64 + lane]);
        Al[kk] = __builtin_bit_cast(bf16x8, xfl[(gA * 4 + kk) * 64 + lane]);
    }

    // lanes 0-31 own one wave-local row each
    float tv[16];
    float worst = FLT_MAX;
#pragma unroll
    for (int j = 0; j < 16; ++j) tv[j] = FLT_MAX;

    int rlbase = 4 * (lane >> 5);        // wave-local row of reg: rlbase+(reg&3)+8*(reg>>2)
    int sub = lane & 31;                 // col within this wave's 32-col stripe
    int colq = wc * 32 + sub;

    for (int chunk = 0; chunk < QCOLS / 64; ++chunk) {
        int c0 = colbase + chunk * 64;
        int gB = ((bglob + c0) >> 5) + wc;
        float sc = sq[bglob + c0 + colq];

        f32x16 acc0, acc1;
#pragma unroll
        for (int i = 0; i < 16; ++i) { acc0[i] = 0.f; acc1[i] = 0.f; }

        // ---- K half 0 (kk = 0,1): 6 B-frags live ----
        {
            bf16x8 Bh0 = __builtin_bit_cast(bf16x8, xfh[(gB * 4 + 0) * 64 + lane]);
            bf16x8 Bm0 = __builtin_bit_cast(bf16x8, xfm[(gB * 4 + 0) * 64 + lane]);
            bf16x8 Bl0 = __builtin_bit_cast(bf16x8, xfl[(gB * 4 + 0) * 64 + lane]);
            bf16x8 Bh1 = __builtin_bit_cast(bf16x8, xfh[(gB * 4 + 1) * 64 + lane]);
            bf16x8 Bm1 = __builtin_bit_cast(bf16x8, xfm[(gB * 4 + 1) * 64 + lane]);
            bf16x8 Bl1 = __builtin_bit_cast(bf16x8, xfl[(gB * 4 + 1) * 64 + lane]);
            acc0 = __builtin_amdgcn_mfma_f32_32x32x16_bf16(Ah[0], Bh0, acc0, 0, 0, 0);
            acc1 = __builtin_amdgcn_mfma_f32_32x32x16_bf16(Ah[0], Bm0, acc1, 0, 0, 0);
            acc0 = __builtin_amdgcn_mfma_f32_32x32x16_bf16(Am[0], Bh0, acc0, 0, 0, 0);
            acc1 = __builtin_amdgcn_mfma_f32_32x32x16_bf16(Am[0], Bm0, acc1, 0, 0, 0);
            acc0 = __builtin_amdgcn_mfma_f32_32x32x16_bf16(Ah[0], Bl0, acc0, 0, 0, 0);
            acc1 = __builtin_amdgcn_mfma_f32_32x32x16_bf16(Al[0], Bh0, acc1, 0, 0, 0);
            acc0 = __builtin_amdgcn_mfma_f32_32x32x16_bf16(Ah[1], Bh1, acc0, 0, 0, 0);
            acc1 = __builtin_amdgcn_mfma_f32_32x32x16_bf16(Ah[1], Bm1, acc1, 0, 0, 0);
            acc0 = __builtin_amdgcn_mfma_f32_32x32x16_bf16(Am[1], Bh1, acc0, 0, 0, 0);
            acc1 = __builtin_amdgcn_mfma_f32_32x32x16_bf16(Am[1], Bm1, acc1, 0, 0, 0);
            acc0 = __builtin_amdgcn_mfma_f32_32x32x16_bf16(Ah[1], Bl1, acc0, 0, 0, 0);
            acc1 = __builtin_amdgcn_mfma_f32_32x32x16_bf16(Al[1], Bh1, acc1, 0, 0, 0);
        }
        __builtin_amdgcn_sched_barrier(0);   // keep half-1 B loads from hoisting
        // ---- K half 1 (kk = 2,3) ----
        {
            bf16x8 Bh2 = __builtin_bit_cast(bf16x8, xfh[(gB * 4 + 2) * 64 + lane]);
            bf16x8 Bm2 = __builtin_bit_cast(bf16x8, xfm[(gB * 4 + 2) * 64 + lane]);
            bf16x8 Bl2 = __builtin_bit_cast(bf16x8, xfl[(gB * 4 + 2) * 64 + lane]);
            bf16x8 Bh3 = __builtin_bit_cast(bf16x8, xfh[(gB * 4 + 3) * 64 + lane]);
            bf16x8 Bm3 = __builtin_bit_cast(bf16x8, xfm[(gB * 4 + 3) * 64 + lane]);
            bf16x8 Bl3 = __builtin_bit_cast(bf16x8, xfl[(gB * 4 + 3) * 64 + lane]);
            acc0 = __builtin_amdgcn_mfma_f32_32x32x16_bf16(Ah[2], Bh2, acc0, 0, 0, 0);
            acc1 = __builtin_amdgcn_mfma_f32_32x32x16_bf16(Ah[2], Bm2, acc1, 0, 0, 0);
            acc0 = __builtin_amdgcn_mfma_f32_32x32x16_bf16(Am[2], Bh2, acc0, 0, 0, 0);
            acc1 = __builtin_amdgcn_mfma_f32_32x32x16_bf16(Am[2], Bm2, acc1, 0, 0, 0);
            acc0 = __builtin_amdgcn_mfma_f32_32x32x16_bf16(Ah[2], Bl2, acc0, 0, 0, 0);
            acc1 = __builtin_amdgcn_mfma_f32_32x32x16_bf16(Al[2], Bh2, acc1, 0, 0, 0);
            acc0 = __builtin_amdgcn_mfma_f32_32x32x16_bf16(Ah[3], Bh3, acc0, 0, 0, 0);
            acc1 = __builtin_amdgcn_mfma_f32_32x32x16_bf16(Ah[3], Bm3, acc1, 0, 0, 0);
            acc0 = __builtin_amdgcn_mfma_f32_32x32x16_bf16(Am[3], Bh3, acc0, 0, 0, 0);
            acc1 = __builtin_amdgcn_mfma_f32_32x32x16_bf16(Am[3], Bm3, acc1, 0, 0, 0);
            acc0 = __builtin_amdgcn_mfma_f32_32x32x16_bf16(Ah[3], Bl3, acc0, 0, 0, 0);
            acc1 = __builtin_amdgcn_mfma_f32_32x32x16_bf16(Al[3], Bh3, acc1, 0, 0, 0);
        }

        if (chunk == 0) {
            // flood: every score survives; slotted write, no atomics
#pragma unroll
            for (int reg = 0; reg < 16; ++reg) {
                float s = fmaf(-2.f, acc0[reg] + acc1[reg], sc);
                int rl = rlbase + (reg & 3) + 8 * (reg >> 2);
                bufvW[rl * 33 + sub] = s;
            }
        } else {
            float4 twA[4];
#pragma unroll
            for (int g4 = 0; g4 < 4; ++g4)
                twA[g4] = *(const float4*)&worstW[rlbase + 8 * g4];
#pragma unroll
            for (int reg = 0; reg < 16; ++reg) {
                float s = fmaf(-2.f, acc0[reg] + acc1[reg], sc);
                float tW = ((const float*)&twA[reg >> 2])[reg & 3];
                if (s < tW) {
                    int rl = rlbase + (reg & 3) + 8 * (reg >> 2);
                    int slot = atomicAdd(&cntW[rl], 1);   // slot < 32 always
                    bufvW[rl * 33 + slot] = s;
                    bufiW[rl * 33 + slot] = (unsigned short)sub;
                }
            }
        }

        // wave-local merge: lane l < 32 merges wave-local row l.
        // Same wave wrote the buffers above -> program order, no barrier.
        if (lane < 32) {
            int n = (chunk == 0) ? 32 : cntW[lane];
            int base = lane * 33;
            int id0 = bglob + c0 + wc * 32;
            for (int k = 0; k < n; ++k) {
                float s = bufvW[base + k];
                if (s < worst) {
                    float mx = tv[0];
                    int pos = 0;
#pragma unroll
                    for (int j = 1; j < 16; ++j) {
                        bool g = tv[j] > mx;
                        mx = g ? tv[j] : mx;
                        pos = g ? j : pos;
                    }
#pragma unroll
                    for (int j = 0; j < 16; ++j)
                        if (j == pos) tv[j] = s;
                    idLW[lane * 17 + pos] = (chunk == 0) ? (id0 + k)
                                                         : (id0 + (int)bufiW[base + k]);
                    float nw = fmaxf(fmaxf(fmaxf(tv[0], tv[1]), fmaxf(tv[2], tv[3])),
                                     fmaxf(fmaxf(tv[4], tv[5]), fmaxf(tv[6], tv[7])));
                    nw = fmaxf(nw, fmaxf(fmaxf(fmaxf(tv[8], tv[9]), fmaxf(tv[10], tv[11])),
                                         fmaxf(fmaxf(tv[12], tv[13]), fmaxf(tv[14], tv[15]))));
                    worst = nw;
                }
            }
            if (n > 0) { cntW[lane] = 0; worstW[lane] = worst; }
        }
        __builtin_amdgcn_sched_barrier(0);   // cap cross-chunk register pressure
    }

    if (lane < 32) {
        int qq = half * 2 + wc;
        size_t o = (((size_t)(bglob + r0 + wr * 32 + lane)) * NPART + qq) * KNN;
#pragma unroll
        for (int j = 0; j < 16; ++j) {
            pv[o + j] = tv[j];
            pi[o + j] = idLW[lane * 17 + j];
        }
    }
}

// ---------------------------------------------------------------------------
// K1b: merge NPART=4 partial top-16 lists per row -> final idx.
// 256 threads = 64 rows x 4 partials per block.
// ---------------------------------------------------------------------------
__global__ void merge_kernel(const float* __restrict__ pv, const int* __restrict__ pi,
                             int* __restrict__ idx_out) {
    __shared__ float mv[64][65];
    __shared__ int   mi[64][65];
    int tid = threadIdx.x;
    int lr = tid & 63, q = tid >> 6;
    int row = blockIdx.x * 64 + lr;
    size_t o = ((size_t)row * NPART + q) * KNN;
#pragma unroll
    for (int j = 0; j < 16; ++j) {
        mv[lr][q * 16 + j] = pv[o + j];
        mi[lr][q * 16 + j] = pi[o + j];
    }
    __syncthreads();
    if (tid < 64) {
        float tv[16];
        int ti[16];
        float worst = FLT_MAX;
#pragma unroll
        for (int j = 0; j < 16; ++j) { tv[j] = FLT_MAX; ti[j] = 0; }
        for (int e = 0; e < 64; ++e) {
            float s = mv[tid][e];
            if (s < worst) {
                float mx = tv[0];
                int pos = 0;
#pragma unroll
                for (int j = 1; j < 16; ++j) {
                    bool g = tv[j] > mx;
                    mx = g ? tv[j] : mx;
                    pos = g ? j : pos;
                }
#pragma unroll
                for (int j = 0; j < 16; ++j)
                    if (j == pos) { tv[j] = s; ti[j] = mi[tid][e]; }
                float nw = tv[0];
#pragma unroll
                for (int j = 1; j < 16; ++j) nw = fmaxf(nw, tv[j]);
                worst = nw;
            }
        }
        size_t oo = (size_t)row * KNN;
#pragma unroll
        for (int j = 0; j < 16; ++j) idx_out[oo + j] = ti[j];
    }
}

// ---------------------------------------------------------------------------
// K2: U = x @ (W1 - W2), V = x @ W2
// ---------------------------------------------------------------------------
__global__ void prep_UV(const float* __restrict__ x, const float* __restrict__ W,
                        float* __restrict__ U, float* __restrict__ V) {
    __shared__ float Ws[128][64];
    __shared__ float xs[4][64];
    int tid = threadIdx.x;
    for (int i = tid; i < 128 * 64; i += 256) ((float*)Ws)[i] = W[i];
    int p0 = blockIdx.x * 4;
    int r = tid >> 6, c = tid & 63;
    xs[r][c] = x[(size_t)(p0 + r) * C + c];
    __syncthreads();
    float u = 0.f, v = 0.f;
#pragma unroll
    for (int k = 0; k < 64; ++k) {
        float xv = xs[r][k];
        float w1 = Ws[k][c];
        float w2 = Ws[64 + k][c];
        u = fmaf(xv, w1 - w2, u);
        v = fmaf(xv, w2, v);
    }
    size_t o = (size_t)(p0 + r) * C + c;
    U[o] = u;
    V[o] = v;
}

// ---------------------------------------------------------------------------
// K3: BN stats
// ---------------------------------------------------------------------------
__global__ void stats_kernel(const float* __restrict__ U, const float* __restrict__ V,
                             const float* __restrict__ bias, const int* __restrict__ idx,
                             float* __restrict__ stats) {
    int tid = threadIdx.x;
    int c = tid & 63, kk = tid >> 6;
    int p0 = blockIdx.x * 32;
    float bc = bias[c];
    float sum = 0.f, sumsq = 0.f;
    for (int pp = 0; pp < 32; ++pp) {
        int p = p0 + pp;
        float u = U[(size_t)p * C + c] + bc;
#pragma unroll
        for (int k4 = 0; k4 < 4; ++k4) {
            int j = idx[(size_t)p * KNN + kk * 4 + k4];
            float h = u + V[(size_t)j * C + c];
            sum += h;
            sumsq = fmaf(h, h, sumsq);
        }
    }
    __shared__ float red[2][4][64];
    red[0][kk][c] = sum;
    red[1][kk][c] = sumsq;
    __syncthreads();
    if (tid < 64) {
        float s = red[0][0][tid] + red[0][1][tid] + red[0][2][tid] + red[0][3][tid];
        atomicAdd(&stats[tid], s);
    } else if (tid < 128) {
        int cc = tid - 64;
        float s = red[1][0][cc] + red[1][1][cc] + red[1][2][cc] + red[1][3][cc];
        atomicAdd(&stats[64 + cc], s);
    }
}

__global__ void finalize_kernel(const float* __restrict__ stats,
                                const float* __restrict__ gamma,
                                const float* __restrict__ beta,
                                float* __restrict__ sshift) {
    int c = threadIdx.x;
    const float N = (float)NEDGE;
    float mean = stats[c] / N;
    float var = stats[64 + c] / N - mean * mean;
    float s = gamma[c] * rsqrtf(var + EPSV);
    sshift[c] = s;
    sshift[64 + c] = beta[c] - mean * s;
}

// ---------------------------------------------------------------------------
// K5: out = lrelu(s*(U+b + max/min_k V[idx]) + t)  (monotone fusion of max_k)
// ---------------------------------------------------------------------------
__global__ void out_kernel(const float* __restrict__ U, const float* __restrict__ V,
                           const float* __restrict__ bias, const int* __restrict__ idx,
                           const float* __restrict__ sshift, float* __restrict__ out) {
    int tid = threadIdx.x;
    int c = tid & 63, g = tid >> 6;
    int p0 = blockIdx.x * 16;
    float s = sshift[c], t = sshift[64 + c];
    float bc = bias[c];
    for (int pp = g; pp < 16; pp += 4) {
        int p = p0 + pp;
        float mx = -FLT_MAX, mn = FLT_MAX;
#pragma unroll
        for (int k = 0; k < KNN; ++k) {
            int j = idx[(size_t)p * KNN + k];
            float v = V[(size_t)j * C + c];
            mx = fmaxf(mx, v);
            mn = fminf(mn, v);
        }
        float hsel = (s >= 0.f) ? mx : mn;
        float hn = fmaf(s, U[(size_t)p * C + c] + bc + hsel, t);
        out[(size_t)p * C + c] = (hn >= 0.f) ? hn : SLOPE * hn;
    }
}

// ---------------------------------------------------------------------------
extern "C" void kernel_launch(void* const* d_in, const int* in_sizes, int n_in,
                              void* d_out, int out_size, void* d_ws, size_t ws_size,
                              hipStream_t stream) {
    const float* x     = (const float*)d_in[0];
    const float* W     = (const float*)d_in[2];
    const float* bias  = (const float*)d_in[3];
    const float* gamma = (const float*)d_in[4];
    const float* beta  = (const float*)d_in[5];
    float* out = (float*)d_out;

    float* wsf    = (float*)d_ws;
    float* U      = wsf;
    float* V      = wsf + 2097152;
    uint4* xfh    = (uint4*)wsf;                   // aliases U/V, dead after knn
    uint4* xfm    = (uint4*)(wsf + 1048576);
    uint4* xfl    = (uint4*)(wsf + 2097152);
    float* sq     = wsf + 4194304;
    float* stats  = wsf + 4227072;
    float* sshift = wsf + 4227200;
    int*   idx    = (int*)(wsf + 4227328);
    float* pv     = wsf + 4751616;
    int*   pi     = (int*)(wsf + 6848768);

    hipLaunchKernelGGL(prep_frag, dim3(NPTS / 32), dim3(256), 0, stream, x, xfh, xfm, xfl, sq);
    hipLaunchKernelGGL(knn_kernel, dim3(BATCH * (P / 64) * NQ), dim3(256), 0, stream,
                       (const uint4*)xfh, (const uint4*)xfm, (const uint4*)xfl, sq, pv, pi);
    hipLaunchKernelGGL(merge_kernel, dim3(NPTS / 64), dim3(256), 0, stream, pv, pi, idx);
    hipLaunchKernelGGL(prep_UV, dim3(NPTS / 4), dim3(256), 0, stream, x, W, U, V);
    hipMemsetAsync(stats, 0, 128 * sizeof(float), stream);
    hipLaunchKernelGGL(stats_kernel, dim3(NPTS / 32), dim3(256), 0, stream, U, V, bias, idx, stats);
    hipLaunchKernelGGL(finalize_kernel, dim3(1), dim3(64), 0, stream, stats, gamma, beta, sshift);
    hipLaunchKernelGGL(out_kernel, dim3(NPTS / 16), dim3(256), 0, stream, U, V, bias, idx, sshift, out);
}

// Round 9
// 578.153 us; speedup vs baseline: 1.0153x; 1.0153x over previous
//
#include <hip/hip_runtime.h>
#include <cfloat>

#define BATCH 4
#define P 8192
#define C 64
#define KNN 16
#define NPTS (BATCH * P)        // 32768
#define NEDGE (NPTS * KNN)      // 524288
#define EPSV 1e-5f
#define SLOPE 0.2f
#define NQ 2                    // column-range split per row-tile
#define QCOLS (P / NQ)          // 4096 cols per block
#define NPART 4                 // partial lists per row = NQ * 2 col-waves

typedef __attribute__((ext_vector_type(8))) short bf16x8;
typedef __attribute__((ext_vector_type(16))) float f32x16;

// ---------------- workspace layout (float element offsets) ----------------
// U      : [NPTS][C]   @ 0          (2097152)   written AFTER knn
// V      : [NPTS][C]   @ 2097152    (2097152)   written AFTER knn
// xfh/xfm/xfl bf16 frags alias U/V region (dead after knn)
// sq     : [NPTS]      @ 4194304    (32768)
// stats  : [128]       @ 4227072
// sshift : [128]       @ 4227200
// idx    : int[NEDGE]  @ 4227328    (524288)
// pv     : [NPTS][4][16] float @ 4751616 (2097152)
// pi     : [NPTS][4][16] int   @ 6848768 (2097152)
// total = 8945920 floats = 34.1 MB

__device__ __forceinline__ unsigned short f2bf(float f) {
    unsigned u = __float_as_uint(f);
    u += 0x7FFFu + ((u >> 16) & 1u);
    return (unsigned short)(u >> 16);
}
__device__ __forceinline__ float bf2f(unsigned short s) {
    return __uint_as_float(((unsigned)s) << 16);
}

// ---------------------------------------------------------------------------
// K0: fragment-layout 3-way bf16 split of x + exact fp32 row norms.
// xf[(g*4+kk)*64 + lane] (uint4 = 8 bf16) holds point g*32+(lane&31),
// k = kk*16 + (lane>>5)*8 .. +8  — the mfma_f32_32x32x16_bf16 operand map.
// ---------------------------------------------------------------------------
__global__ void prep_frag(const float* __restrict__ x, uint4* __restrict__ xfh,
                          uint4* __restrict__ xfm, uint4* __restrict__ xfl,
                          float* __restrict__ sq) {
    __shared__ float part[32][9];
    int tid = threadIdx.x;
    int ptl = tid >> 3, j8 = tid & 7;
    int g = blockIdx.x;
    int p = g * 32 + ptl;
    const float4* xp = (const float4*)(x + (size_t)p * C + j8 * 8);
    float4 a = xp[0], b = xp[1];
    float v[8] = {a.x, a.y, a.z, a.w, b.x, b.y, b.z, b.w};
    unsigned short hs[8], ms[8], ls[8];
    float ssum = 0.f;
#pragma unroll
    for (int e = 0; e < 8; ++e) {
        float xv = v[e];
        ssum = fmaf(xv, xv, ssum);
        unsigned short h = f2bf(xv);
        float r1 = xv - bf2f(h);
        unsigned short m = f2bf(r1);
        float r2 = r1 - bf2f(m);
        unsigned short l = f2bf(r2);
        hs[e] = h; ms[e] = m; ls[e] = l;
    }
    int dst = (g * 4 + (j8 >> 1)) * 64 + ptl + 32 * (j8 & 1);
    uint4 ph, pm, pl;
    ph.x = (unsigned)hs[0] | ((unsigned)hs[1] << 16);
    ph.y = (unsigned)hs[2] | ((unsigned)hs[3] << 16);
    ph.z = (unsigned)hs[4] | ((unsigned)hs[5] << 16);
    ph.w = (unsigned)hs[6] | ((unsigned)hs[7] << 16);
    pm.x = (unsigned)ms[0] | ((unsigned)ms[1] << 16);
    pm.y = (unsigned)ms[2] | ((unsigned)ms[3] << 16);
    pm.z = (unsigned)ms[4] | ((unsigned)ms[5] << 16);
    pm.w = (unsigned)ms[6] | ((unsigned)ms[7] << 16);
    pl.x = (unsigned)ls[0] | ((unsigned)ls[1] << 16);
    pl.y = (unsigned)ls[2] | ((unsigned)ls[3] << 16);
    pl.z = (unsigned)ls[4] | ((unsigned)ls[5] << 16);
    pl.w = (unsigned)ls[6] | ((unsigned)ls[7] << 16);
    xfh[dst] = ph; xfm[dst] = pm; xfl[dst] = pl;
    part[ptl][j8] = ssum;
    __syncthreads();
    if (j8 == 0) {
        float s = 0.f;
#pragma unroll
        for (int k = 0; k < 8; ++k) s += part[ptl][k];
        sq[p] = s;
    }
}

// ---------------------------------------------------------------------------
// K1: KNN partial — wave-autonomous (zero barriers), register-slimmed.
// Wave (wr,wc) computes its 32x32 quadrant; private per-row top-16 in its
// own LDS region (program-order consistency, no __syncthreads). r8 lesson:
// (256,4) = 128 unified VGPR+AGPR per wave; r8's live set (A48+B24+acc32+
// tv16+misc) = ~140 spilled (VALUBusy 54% = accvgpr/scratch copies).
// r9 cuts: SINGLE acc chain (16 regs) + per-kk B staging capped by
// sched_barrier (12 regs live) -> ~112 live, no spill, 4 blocks/CU.
// Per-kk load stall (~200cyc L2) is hidden by 16 barrier-free waves/CU.
// ---------------------------------------------------------------------------
__global__ __launch_bounds__(256, 4) void knn_kernel(const uint4* __restrict__ xfh,
                                                     const uint4* __restrict__ xfm,
                                                     const uint4* __restrict__ xfl,
                                                     const float* __restrict__ sq,
                                                     float* __restrict__ pv,
                                                     int* __restrict__ pi) {
    __shared__ float          bufv[4 * 32 * 33];   // per-wave survivor values
    __shared__ unsigned short bufi[4 * 32 * 33];   // per-wave survivor col-subs
    __shared__ int            idL [4 * 32 * 17];   // per-wave top-16 ids
    __shared__ int            cntL[4 * 32];
    __shared__ float          worstL[4 * 32];

    int tid = threadIdx.x;
    int b = blockIdx.x & 3;              // batch -> XCDs {b, b+4}: frags L2-resident
    int t = blockIdx.x >> 2;
    int tile = t & 127;
    int half = t >> 7;
    int bglob = b * P;
    int r0 = tile * 64;
    int colbase = half * QCOLS;
    int w = tid >> 6, lane = tid & 63;
    int wr = w & 1, wc = w >> 1;

    float*          bufvW = bufv + w * (32 * 33);
    unsigned short* bufiW = bufi + w * (32 * 33);
    int*            idLW  = idL  + w * (32 * 17);
    int*            cntW  = cntL + w * 32;
    float*          worstW = worstL + w * 32;

    if (lane < 32) { cntW[lane] = 0; worstW[lane] = FLT_MAX; }

    // persistent A fragments for this wave's 32 rows (48 VGPRs)
    int gA = ((bglob + r0) >> 5) + wr;
    bf16x8 Ah[4], Am[4], Al[4];
#pragma unroll
    for (int kk = 0; kk < 4; ++kk) {
        Ah[kk] = __builtin_bit_cast(bf16x8, xfh[(gA * 4 + kk) * 64 + lane]);
        Am[kk] = __builtin_bit_cast(bf16x8, xfm[(gA * 4 + kk) * 64 + lane]);
        Al[kk] = __builtin_bit_cast(bf16x8, xfl[(gA * 4 + kk) * 64 + lane]);
    }

    // lanes 0-31 own one wave-local row each
    float tv[16];
    float worst = FLT_MAX;
#pragma unroll
    for (int j = 0; j < 16; ++j) tv[j] = FLT_MAX;

    int rlbase = 4 * (lane >> 5);        // wave-local row of reg: rlbase+(reg&3)+8*(reg>>2)
    int sub = lane & 31;                 // col within this wave's 32-col stripe
    int colq = wc * 32 + sub;

    for (int chunk = 0; chunk < QCOLS / 64; ++chunk) {
        int c0 = colbase + chunk * 64;
        int gB = ((bglob + c0) >> 5) + wc;
        float sc = sq[bglob + c0 + colq];

        f32x16 acc;
#pragma unroll
        for (int i = 0; i < 16; ++i) acc[i] = 0.f;

        // single acc chain; per-kk B staging (3 frags live at a time)
#pragma unroll
        for (int kk = 0; kk < 4; ++kk) {
            bf16x8 Bh = __builtin_bit_cast(bf16x8, xfh[(gB * 4 + kk) * 64 + lane]);
            bf16x8 Bm = __builtin_bit_cast(bf16x8, xfm[(gB * 4 + kk) * 64 + lane]);
            bf16x8 Bl = __builtin_bit_cast(bf16x8, xfl[(gB * 4 + kk) * 64 + lane]);
            acc = __builtin_amdgcn_mfma_f32_32x32x16_bf16(Ah[kk], Bh, acc, 0, 0, 0);
            acc = __builtin_amdgcn_mfma_f32_32x32x16_bf16(Am[kk], Bh, acc, 0, 0, 0);
            acc = __builtin_amdgcn_mfma_f32_32x32x16_bf16(Al[kk], Bh, acc, 0, 0, 0);
            acc = __builtin_amdgcn_mfma_f32_32x32x16_bf16(Ah[kk], Bm, acc, 0, 0, 0);
            acc = __builtin_amdgcn_mfma_f32_32x32x16_bf16(Am[kk], Bm, acc, 0, 0, 0);
            acc = __builtin_amdgcn_mfma_f32_32x32x16_bf16(Ah[kk], Bl, acc, 0, 0, 0);
            __builtin_amdgcn_sched_barrier(0);   // cap B liveness at one kk group
        }

        if (chunk == 0) {
            // flood: every score survives; slotted write, no atomics
#pragma unroll
            for (int reg = 0; reg < 16; ++reg) {
                float s = fmaf(-2.f, acc[reg], sc);
                int rl = rlbase + (reg & 3) + 8 * (reg >> 2);
                bufvW[rl * 33 + sub] = s;
            }
        } else {
            float4 twA[4];
#pragma unroll
            for (int g4 = 0; g4 < 4; ++g4)
                twA[g4] = *(const float4*)&worstW[rlbase + 8 * g4];
#pragma unroll
            for (int reg = 0; reg < 16; ++reg) {
                float s = fmaf(-2.f, acc[reg], sc);
                float tW = ((const float*)&twA[reg >> 2])[reg & 3];
                if (s < tW) {
                    int rl = rlbase + (reg & 3) + 8 * (reg >> 2);
                    int slot = atomicAdd(&cntW[rl], 1);   // slot < 32 always
                    bufvW[rl * 33 + slot] = s;
                    bufiW[rl * 33 + slot] = (unsigned short)sub;
                }
            }
        }

        // wave-local merge: lane l < 32 merges wave-local row l.
        // Same wave wrote the buffers above -> program order, no barrier.
        if (lane < 32) {
            int n = (chunk == 0) ? 32 : cntW[lane];
            int base = lane * 33;
            int id0 = bglob + c0 + wc * 32;
            for (int k = 0; k < n; ++k) {
                float s = bufvW[base + k];
                if (s < worst) {
                    float mx = tv[0];
                    int pos = 0;
#pragma unroll
                    for (int j = 1; j < 16; ++j) {
                        bool g = tv[j] > mx;
                        mx = g ? tv[j] : mx;
                        pos = g ? j : pos;
                    }
#pragma unroll
                    for (int j = 0; j < 16; ++j)
                        if (j == pos) tv[j] = s;
                    idLW[lane * 17 + pos] = (chunk == 0) ? (id0 + k)
                                                         : (id0 + (int)bufiW[base + k]);
                    float nw = fmaxf(fmaxf(fmaxf(tv[0], tv[1]), fmaxf(tv[2], tv[3])),
                                     fmaxf(fmaxf(tv[4], tv[5]), fmaxf(tv[6], tv[7])));
                    nw = fmaxf(nw, fmaxf(fmaxf(fmaxf(tv[8], tv[9]), fmaxf(tv[10], tv[11])),
                                         fmaxf(fmaxf(tv[12], tv[13]), fmaxf(tv[14], tv[15]))));
                    worst = nw;
                }
            }
            if (n > 0) { cntW[lane] = 0; worstW[lane] = worst; }
        }
        __builtin_amdgcn_sched_barrier(0);   // keep chunks from overlapping regs
    }

    if (lane < 32) {
        int qq = half * 2 + wc;
        size_t o = (((size_t)(bglob + r0 + wr * 32 + lane)) * NPART + qq) * KNN;
#pragma unroll
        for (int j = 0; j < 16; ++j) {
            pv[o + j] = tv[j];
            pi[o + j] = idLW[lane * 17 + j];
        }
    }
}

// ---------------------------------------------------------------------------
// K1b: merge NPART=4 partial top-16 lists per row -> final idx.
// 256 threads = 64 rows x 4 partials per block.
// ---------------------------------------------------------------------------
__global__ void merge_kernel(const float* __restrict__ pv, const int* __restrict__ pi,
                             int* __restrict__ idx_out) {
    __shared__ float mv[64][65];
    __shared__ int   mi[64][65];
    int tid = threadIdx.x;
    int lr = tid & 63, q = tid >> 6;
    int row = blockIdx.x * 64 + lr;
    size_t o = ((size_t)row * NPART + q) * KNN;
#pragma unroll
    for (int j = 0; j < 16; ++j) {
        mv[lr][q * 16 + j] = pv[o + j];
        mi[lr][q * 16 + j] = pi[o + j];
    }
    __syncthreads();
    if (tid < 64) {
        float tv[16];
        int ti[16];
        float worst = FLT_MAX;
#pragma unroll
        for (int j = 0; j < 16; ++j) { tv[j] = FLT_MAX; ti[j] = 0; }
        for (int e = 0; e < 64; ++e) {
            float s = mv[tid][e];
            if (s < worst) {
                float mx = tv[0];
                int pos = 0;
#pragma unroll
                for (int j = 1; j < 16; ++j) {
                    bool g = tv[j] > mx;
                    mx = g ? tv[j] : mx;
                    pos = g ? j : pos;
                }
#pragma unroll
                for (int j = 0; j < 16; ++j)
                    if (j == pos) { tv[j] = s; ti[j] = mi[tid][e]; }
                float nw = tv[0];
#pragma unroll
                for (int j = 1; j < 16; ++j) nw = fmaxf(nw, tv[j]);
                worst = nw;
            }
        }
        size_t oo = (size_t)row * KNN;
#pragma unroll
        for (int j = 0; j < 16; ++j) idx_out[oo + j] = ti[j];
    }
}

// ---------------------------------------------------------------------------
// K2: U = x @ (W1 - W2), V = x @ W2
// ---------------------------------------------------------------------------
__global__ void prep_UV(const float* __restrict__ x, const float* __restrict__ W,
                        float* __restrict__ U, float* __restrict__ V) {
    __shared__ float Ws[128][64];
    __shared__ float xs[4][64];
    int tid = threadIdx.x;
    for (int i = tid; i < 128 * 64; i += 256) ((float*)Ws)[i] = W[i];
    int p0 = blockIdx.x * 4;
    int r = tid >> 6, c = tid & 63;
    xs[r][c] = x[(size_t)(p0 + r) * C + c];
    __syncthreads();
    float u = 0.f, v = 0.f;
#pragma unroll
    for (int k = 0; k < 64; ++k) {
        float xv = xs[r][k];
        float w1 = Ws[k][c];
        float w2 = Ws[64 + k][c];
        u = fmaf(xv, w1 - w2, u);
        v = fmaf(xv, w2, v);
    }
    size_t o = (size_t)(p0 + r) * C + c;
    U[o] = u;
    V[o] = v;
}

// ---------------------------------------------------------------------------
// K3: BN stats
// ---------------------------------------------------------------------------
__global__ void stats_kernel(const float* __restrict__ U, const float* __restrict__ V,
                             const float* __restrict__ bias, const int* __restrict__ idx,
                             float* __restrict__ stats) {
    int tid = threadIdx.x;
    int c = tid & 63, kk = tid >> 6;
    int p0 = blockIdx.x * 32;
    float bc = bias[c];
    float sum = 0.f, sumsq = 0.f;
    for (int pp = 0; pp < 32; ++pp) {
        int p = p0 + pp;
        float u = U[(size_t)p * C + c] + bc;
#pragma unroll
        for (int k4 = 0; k4 < 4; ++k4) {
            int j = idx[(size_t)p * KNN + kk * 4 + k4];
            float h = u + V[(size_t)j * C + c];
            sum += h;
            sumsq = fmaf(h, h, sumsq);
        }
    }
    __shared__ float red[2][4][64];
    red[0][kk][c] = sum;
    red[1][kk][c] = sumsq;
    __syncthreads();
    if (tid < 64) {
        float s = red[0][0][tid] + red[0][1][tid] + red[0][2][tid] + red[0][3][tid];
        atomicAdd(&stats[tid], s);
    } else if (tid < 128) {
        int cc = tid - 64;
        float s = red[1][0][cc] + red[1][1][cc] + red[1][2][cc] + red[1][3][cc];
        atomicAdd(&stats[64 + cc], s);
    }
}

__global__ void finalize_kernel(const float* __restrict__ stats,
                                const float* __restrict__ gamma,
                                const float* __restrict__ beta,
                                float* __restrict__ sshift) {
    int c = threadIdx.x;
    const float N = (float)NEDGE;
    float mean = stats[c] / N;
    float var = stats[64 + c] / N - mean * mean;
    float s = gamma[c] * rsqrtf(var + EPSV);
    sshift[c] = s;
    sshift[64 + c] = beta[c] - mean * s;
}

// ---------------------------------------------------------------------------
// K5: out = lrelu(s*(U+b + max/min_k V[idx]) + t)  (monotone fusion of max_k)
// ---------------------------------------------------------------------------
__global__ void out_kernel(const float* __restrict__ U, const float* __restrict__ V,
                           const float* __restrict__ bias, const int* __restrict__ idx,
                           const float* __restrict__ sshift, float* __restrict__ out) {
    int tid = threadIdx.x;
    int c = tid & 63, g = tid >> 6;
    int p0 = blockIdx.x * 16;
    float s = sshift[c], t = sshift[64 + c];
    float bc = bias[c];
    for (int pp = g; pp < 16; pp += 4) {
        int p = p0 + pp;
        float mx = -FLT_MAX, mn = FLT_MAX;
#pragma unroll
        for (int k = 0; k < KNN; ++k) {
            int j = idx[(size_t)p * KNN + k];
            float v = V[(size_t)j * C + c];
            mx = fmaxf(mx, v);
            mn = fminf(mn, v);
        }
        float hsel = (s >= 0.f) ? mx : mn;
        float hn = fmaf(s, U[(size_t)p * C + c] + bc + hsel, t);
        out[(size_t)p * C + c] = (hn >= 0.f) ? hn : SLOPE * hn;
    }
}

// ---------------------------------------------------------------------------
extern "C" void kernel_launch(void* const* d_in, const int* in_sizes, int n_in,
                              void* d_out, int out_size, void* d_ws, size_t ws_size,
                              hipStream_t stream) {
    const float* x     = (const float*)d_in[0];
    const float* W     = (const float*)d_in[2];
    const float* bias  = (const float*)d_in[3];
    const float* gamma = (const float*)d_in[4];
    const float* beta  = (const float*)d_in[5];
    float* out = (float*)d_out;

    float* wsf    = (float*)d_ws;
    float* U      = wsf;
    float* V      = wsf + 2097152;
    uint4* xfh    = (uint4*)wsf;                   // aliases U/V, dead after knn
    uint4* xfm    = (uint4*)(wsf + 1048576);
    uint4* xfl    = (uint4*)(wsf + 2097152);
    float* sq     = wsf + 4194304;
    float* stats  = wsf + 4227072;
    float* sshift = wsf + 4227200;
    int*   idx    = (int*)(wsf + 4227328);
    float* pv     = wsf + 4751616;
    int*   pi     = (int*)(wsf + 6848768);

    hipLaunchKernelGGL(prep_frag, dim3(NPTS / 32), dim3(256), 0, stream, x, xfh, xfm, xfl, sq);
    hipLaunchKernelGGL(knn_kernel, dim3(BATCH * (P / 64) * NQ), dim3(256), 0, stream,
                       (const uint4*)xfh, (const uint4*)xfm, (const uint4*)xfl, sq, pv, pi);
    hipLaunchKernelGGL(merge_kernel, dim3(NPTS / 64), dim3(256), 0, stream, pv, pi, idx);
    hipLaunchKernelGGL(prep_UV, dim3(NPTS / 4), dim3(256), 0, stream, x, W, U, V);
    hipMemsetAsync(stats, 0, 128 * sizeof(float), stream);
    hipLaunchKernelGGL(stats_kernel, dim3(NPTS / 32), dim3(256), 0, stream, U, V, bias, idx, stats);
    hipLaunchKernelGGL(finalize_kernel, dim3(1), dim3(64), 0, stream, stats, gamma, beta, sshift);
    hipLaunchKernelGGL(out_kernel, dim3(NPTS / 16), dim3(256), 0, stream, U, V, bias, idx, sshift, out);
}